// Round 6
// baseline (573.555 us; speedup 1.0000x reference)
//
#include <hip/hip_runtime.h>
#include <hip/hip_bf16.h>
#include <stdint.h>

typedef __hip_bfloat16 bf16;
typedef __attribute__((ext_vector_type(8))) short short8;
typedef __attribute__((ext_vector_type(4))) short short4v;
typedef __attribute__((ext_vector_type(4))) float f32x4;

constexpr int cB = 16384, cD = 512, cH = 1024, cS = 8, cE = 4, cDH = 256;

__device__ __forceinline__ float tof(bf16 v) { return __bfloat162float(v); }
__device__ __forceinline__ bf16 tob(float v) { return __float2bfloat16(v); }
__device__ __forceinline__ float b2f(short s) {
  uint32_t u = ((uint32_t)(uint16_t)s) << 16;
  return __builtin_bit_cast(float, u);
}
__device__ __forceinline__ float ldf(const void* p, long i, int isbf) {
  return isbf ? b2f(((const short*)p)[i]) : ((const float*)p)[i];
}

__device__ __forceinline__ void gload_lds16(const bf16* g, char* l) {
  __builtin_amdgcn_global_load_lds(
      (const __attribute__((address_space(1))) void*)g,
      (__attribute__((address_space(3))) void*)l, 16, 0, 0);
}

// ---- dtype probe ----
__global__ __launch_bounds__(256) void probe_k(const void* x, int* flag) {
  __shared__ int sh[256];
  const unsigned short* u = (const unsigned short*)x;
  int cnt = 0;
  for (int i = threadIdx.x; i < 2048; i += 256) {
    float v = fabsf(b2f((short)u[2 * i]));
    cnt += (v > 1e-5f && v < 1e3f) ? 1 : 0;
  }
  sh[threadIdx.x] = cnt;
  __syncthreads();
  for (int s = 128; s > 0; s >>= 1) {
    if (threadIdx.x < s) sh[threadIdx.x] += sh[threadIdx.x + s];
    __syncthreads();
  }
  if (threadIdx.x == 0) flag[0] = (sh[0] > 1024) ? 1 : 0;
}

__global__ __launch_bounds__(256) void cvtx_k(const void* x, bf16* xb, const int* flag) {
  int g = blockIdx.x * 256 + threadIdx.x;
  if (flag[0]) {
    ((short8*)xb)[g] = ((const short8*)x)[g];
  } else {
    const f32x4* xf = (const f32x4*)x;
    f32x4 v0 = xf[2 * g], v1 = xf[2 * g + 1];
    short8 o;
#pragma unroll
    for (int j = 0; j < 4; j++) {
      o[j] = __builtin_bit_cast(short, tob(v0[j]));
      o[j + 4] = __builtin_bit_cast(short, tob(v1[j]));
    }
    ((short8*)xb)[g] = o;
  }
}

struct CvtDesc {
  const void* src[11];
  int off[12];
};
__global__ __launch_bounds__(256) void cvt_smalls_k(CvtDesc d, const int* flag, float* dst) {
  int i = blockIdx.x * 256 + threadIdx.x;
  if (i >= d.off[11]) return;
  int isb = flag[0];
  int j = 0;
  while (i >= d.off[j + 1]) j++;
  dst[i] = ldf(d.src[j], i - d.off[j], isb);
}

__global__ __launch_bounds__(256) void transpose_k(const void* in, bf16* out, int ldin, int ldout,
                                                   long in_off, long in_bs, long out_bs,
                                                   const int* flag) {
  __shared__ float tile[32][33];
  int isb = flag[0];
  long src0 = in_off + (long)blockIdx.z * in_bs;
  bf16* dst = out + (long)blockIdx.z * out_bs;
  int c0 = blockIdx.x * 32, r0 = blockIdx.y * 32;
  int tx = threadIdx.x & 31, ty = threadIdx.x >> 5;
#pragma unroll
  for (int i = 0; i < 4; i++)
    tile[ty + i * 8][tx] = ldf(in, src0 + (long)(r0 + ty + i * 8) * ldin + c0 + tx, isb);
  __syncthreads();
#pragma unroll
  for (int i = 0; i < 4; i++)
    dst[(long)(c0 + ty + i * 8) * ldout + r0 + tx] = tob(tile[tx][ty + i * 8]);
}

// ================  legacy 128x128 GEMM engine (proven r2-r5)  ================
struct GArgs {
  const bf16* A; int lda;
  const bf16* Bt; int ldb; long bt_stride;
  void* C; int ldc;
  int M, N, K;
  const float* bias; int bias_stride;
  const float* gates; int eidx;
  const int* perm; const int* cum;
  const bf16* P1; const float* wsel;
  const int* dflag;
};

template <int EPI, bool GROUPED, bool GATHER_A, bool SCATTER_C>
__global__ __launch_bounds__(256, 4) void gemm_k(GArgs a) {
  __shared__ char smem[32768];
  char* ldsA = smem;
  char* ldsB = smem + 16384;

  int bxs, bys;
  if constexpr (!GROUPED) {
    const int gx = gridDim.x;
    const int nwg = gx * gridDim.y;
    const int d = blockIdx.y * gx + blockIdx.x;
    const int q = nwg >> 3, r = nwg & 7;
    const int xcd = d & 7, di = d >> 3;
    const int logical = (xcd < r ? xcd * (q + 1) : r * (q + 1) + (xcd - r) * q) + di;
    bxs = logical % gx;
    bys = logical / gx;
  } else {
    bxs = blockIdx.x;
    bys = blockIdx.y;
  }

  int g0, cnt;
  if constexpr (GROUPED) {
    int z = blockIdx.z;
    g0 = a.cum[z];
    cnt = a.cum[z + 1] - g0;
  } else {
    g0 = 0;
    cnt = a.M;
  }
  const int ptile = bys * 128;
  if (ptile >= cnt) return;
  const int n0 = bxs * 128;

  const int t = threadIdx.x, w = t >> 6, l = t & 63;
  const int wm = w >> 1, wn = w & 1;

  const bf16* bt = a.Bt + (GROUPED ? (long)blockIdx.z * a.bt_stride : 0);
  const float* bias = a.bias ? (a.bias + (GROUPED ? blockIdx.z * a.bias_stride : 0)) : nullptr;

  const bf16* aSrc[4];
  const bf16* bSrc[4];
  int ldsOff[4];
#pragma unroll
  for (int c = 0; c < 4; c++) {
    int pos = w * 4096 + c * 1024 + l * 16;
    int row = pos >> 7;
    int su = ((((pos >> 4) & 7) ^ (row & 7))) * 8;
    int p = ptile + row;
    if (p > cnt - 1) p = cnt - 1;
    int ar;
    if constexpr (GATHER_A) ar = a.perm[g0 + p];
    else ar = g0 + p;
    aSrc[c] = a.A + (long)ar * a.lda + su;
    bSrc[c] = bt + (long)(n0 + row) * a.ldb + su;
    ldsOff[c] = w * 4096 + c * 1024;
  }

  f32x4 zero = {0.f, 0.f, 0.f, 0.f};
  f32x4 acc[4][4];
#pragma unroll
  for (int i = 0; i < 4; i++)
#pragma unroll
    for (int j = 0; j < 4; j++) acc[i][j] = zero;

  const int nkt = a.K >> 6;
  for (int kt = 0; kt < nkt; ++kt) {
#pragma unroll
    for (int c = 0; c < 4; c++) gload_lds16(aSrc[c] + kt * 64, ldsA + ldsOff[c]);
#pragma unroll
    for (int c = 0; c < 4; c++) gload_lds16(bSrc[c] + kt * 64, ldsB + ldsOff[c]);
    __syncthreads();
#pragma unroll
    for (int kk = 0; kk < 2; kk++) {
      short8 af[4], bv[4];
#pragma unroll
      for (int mi = 0; mi < 4; mi++) {
        int row = wm * 64 + mi * 16 + (l & 15);
        int kg = kk * 4 + (l >> 4);
        int off = row * 128 + ((kg ^ (row & 7)) << 4);
        af[mi] = *(const short8*)(ldsA + off);
      }
#pragma unroll
      for (int ni = 0; ni < 4; ni++) {
        int row = wn * 64 + ni * 16 + (l & 15);
        int kg = kk * 4 + (l >> 4);
        int off = row * 128 + ((kg ^ (row & 7)) << 4);
        bv[ni] = *(const short8*)(ldsB + off);
      }
#pragma unroll
      for (int mi = 0; mi < 4; mi++)
#pragma unroll
        for (int ni = 0; ni < 4; ni++)
          acc[mi][ni] =
              __builtin_amdgcn_mfma_f32_16x16x32_bf16(af[mi], bv[ni], acc[mi][ni], 0, 0, 0);
    }
    __syncthreads();
  }

  const int l15 = l & 15, lg4 = l >> 4;
  int outbf = 1;
  if constexpr (EPI == 5) outbf = a.dflag[0];
#pragma unroll
  for (int mi = 0; mi < 4; mi++) {
#pragma unroll
    for (int j = 0; j < 4; j++) {
      int p = ptile + wm * 64 + mi * 16 + lg4 * 4 + j;
      if (p >= cnt) continue;
      int crow;
      if constexpr (SCATTER_C) crow = a.perm[g0 + p];
      else crow = g0 + p;
#pragma unroll
      for (int ni = 0; ni < 4; ni++) {
        int n = n0 + wn * 64 + ni * 16 + l15;
        float v = acc[mi][ni][j];
        if constexpr (EPI == 1) {
          v += bias[n];
          v = fmaxf(v, 0.f);
          ((bf16*)a.C)[(long)crow * a.ldc + n] = tob(v);
        } else if constexpr (EPI == 2) {
          float g = a.gates[(long)(g0 + p) * 4 + a.eidx];
          v = g * (v + bias[n]);
          float* Cf = (float*)a.C;
          long idx = (long)crow * a.ldc + n;
          if (a.eidx == 0) Cf[idx] = v;
          else Cf[idx] += v;
        } else if constexpr (EPI == 3) {
          ((float*)a.C)[(long)crow * a.ldc + n] = v;
        } else if constexpr (EPI == 4) {
          v += bias[n];
          ((bf16*)a.C)[(long)crow * a.ldc + n] = tob(v);
        } else if constexpr (EPI == 5) {
          float o = tof(a.P1[(long)crow * a.N + n]) + a.wsel[crow] * v + bias[n];
          if (outbf) ((bf16*)a.C)[(long)crow * a.ldc + n] = tob(o);
          else ((float*)a.C)[(long)crow * a.ldc + n] = o;
        } else if constexpr (EPI == 6) {
          float g = a.gates[(long)(g0 + p) * 4 + (n >> 10)];
          v = g * fmaxf(v + bias[n], 0.f);
          ((bf16*)a.C)[(long)crow * a.ldc + n] = tob(v);
        } else if constexpr (EPI == 7) {
          const float* gr = a.gates + (long)(g0 + p) * 4;
          v += gr[0] * bias[n] + gr[1] * bias[512 + n] + gr[2] * bias[1024 + n] +
               gr[3] * bias[1536 + n];
          ((bf16*)a.C)[(long)crow * a.ldc + n] = tob(v);
        } else if constexpr (EPI == 8) {
          ((bf16*)a.C)[(long)crow * a.ldc + n] = tob(v);
        }
      }
    }
  }
}

// ================  256x256 deep-pipelined GEMM engine (T3/T4/T5)  ================
// BM=BN=256, BK=64, 512 threads = 8 waves (2M x 4N), per-wave 128x64 out.
// LDS: 2 buffers x (A 32KB + B 32KB) = 128KB dynamic. Same 16B-unit XOR swizzle
// as legacy engine (pre-swizzled global source, linear LDS dest, XOR on read).
// Pipeline per K-tile: [vmcnt(8); barrier] -> 4 sub-phases {ds_read chunk;
// setprio(1); 16 MFMA; setprio(0)} -> [barrier] -> stage tile t+2 into the
// buffer just drained. vmcnt(8) = 1 staged tile (8 gloads) allowed in flight.
// Race-safety: stage of tile t+2 -> buf[t&1] is issued only after the barrier
// that ends ALL waves' reads of tile t; its landing is enforced by
// vmcnt(8)+barrier before tile t+2's reads. Never vmcnt(0) in steady state.
struct G6Args {
  const bf16* A;       // [M x K], row stride K
  const bf16* Bt;      // [N x K], row stride K
  void* C;
  int N, K, ldc;
  const float* bias;
  const float* gates;
  const bf16* P1;
  const float* wsel;
  const int* dflag;
};

template <int EPI>
__global__ __launch_bounds__(512, 1) void gemm256_k(G6Args a) {
  extern __shared__ char sm[];
  const int t = threadIdx.x, w = t >> 6, l = t & 63;
  const int wm = w >> 2, wn = w & 3;  // 2 x 4 waves

  // XCD-aware bijective remap (grid is exact, no early exit)
  const int gx = gridDim.x;
  const int nwg = gx * gridDim.y;
  const int d = blockIdx.y * gx + blockIdx.x;
  const int q = nwg >> 3, r = nwg & 7;
  const int xcd = d & 7, di = d >> 3;
  const int logical = (xcd < r ? xcd * (q + 1) : r * (q + 1) + (xcd - r) * q) + di;
  const int m0 = (logical / gx) * 256, n0 = (logical % gx) * 256;

  // staging descriptors: 4 rounds A + 4 rounds B per K-tile, 16B/lane
  const bf16* aS[4];
  const bf16* bS[4];
  int ldsO[4];
#pragma unroll
  for (int c = 0; c < 4; c++) {
    int pos = c * 8192 + t * 16;                  // byte pos in 32KB operand tile
    int row = pos >> 7;                           // 128B per row (64 bf16)
    int su = (((pos >> 4) & 7) ^ (row & 7)) * 8;  // pre-swizzled source k-offset
    aS[c] = a.A + (long)(m0 + row) * a.K + su;
    bS[c] = a.Bt + (long)(n0 + row) * a.K + su;
    ldsO[c] = c * 8192 + (w << 10);  // wave-uniform LDS base
  }
  auto stage = [&](int kt, int bb) {
#pragma unroll
    for (int c = 0; c < 4; c++) gload_lds16(aS[c] + kt * 64, sm + bb * 65536 + ldsO[c]);
#pragma unroll
    for (int c = 0; c < 4; c++) gload_lds16(bS[c] + kt * 64, sm + bb * 65536 + 32768 + ldsO[c]);
  };
  auto rdA = [&](int bb, int mi, int kk) -> short8 {
    int row = wm * 128 + mi * 16 + (l & 15);
    int kg = kk * 4 + (l >> 4);
    return *(const short8*)(sm + bb * 65536 + row * 128 + ((kg ^ (row & 7)) << 4));
  };
  auto rdB = [&](int bb, int ni, int kk) -> short8 {
    int row = wn * 64 + ni * 16 + (l & 15);
    int kg = kk * 4 + (l >> 4);
    return *(const short8*)(sm + bb * 65536 + 32768 + row * 128 + ((kg ^ (row & 7)) << 4));
  };

  f32x4 acc[8][4];
#pragma unroll
  for (int i = 0; i < 8; i++)
#pragma unroll
    for (int j = 0; j < 4; j++) acc[i][j] = {0.f, 0.f, 0.f, 0.f};

  const int nkt = a.K >> 6;
  stage(0, 0);
  stage(1, 1);

  for (int kt = 0; kt < nkt; ++kt) {
    const int bb = kt & 1;
    if (kt + 1 < nkt) {
      asm volatile("s_waitcnt vmcnt(8)" ::: "memory");
    } else {
      asm volatile("s_waitcnt vmcnt(0)" ::: "memory");
    }
    __builtin_amdgcn_sched_barrier(0);
    __builtin_amdgcn_s_barrier();
    __builtin_amdgcn_sched_barrier(0);

    short8 fa[4][2], fb0[2][2], fb1[2][2];
    // P1: A lower half + B lower half -> quadrant (0-3, 0-1)
#pragma unroll
    for (int mi = 0; mi < 4; mi++)
#pragma unroll
      for (int kk = 0; kk < 2; kk++) fa[mi][kk] = rdA(bb, mi, kk);
#pragma unroll
    for (int ni = 0; ni < 2; ni++)
#pragma unroll
      for (int kk = 0; kk < 2; kk++) fb0[ni][kk] = rdB(bb, ni, kk);
    __builtin_amdgcn_s_setprio(1);
#pragma unroll
    for (int mi = 0; mi < 4; mi++)
#pragma unroll
      for (int ni = 0; ni < 2; ni++)
#pragma unroll
        for (int kk = 0; kk < 2; kk++)
          acc[mi][ni] = __builtin_amdgcn_mfma_f32_16x16x32_bf16(fa[mi][kk], fb0[ni][kk],
                                                                acc[mi][ni], 0, 0, 0);
    __builtin_amdgcn_s_setprio(0);
    // P2: B upper half -> quadrant (0-3, 2-3)
#pragma unroll
    for (int ni = 0; ni < 2; ni++)
#pragma unroll
      for (int kk = 0; kk < 2; kk++) fb1[ni][kk] = rdB(bb, ni + 2, kk);
    __builtin_amdgcn_s_setprio(1);
#pragma unroll
    for (int mi = 0; mi < 4; mi++)
#pragma unroll
      for (int ni = 0; ni < 2; ni++)
#pragma unroll
        for (int kk = 0; kk < 2; kk++)
          acc[mi][ni + 2] = __builtin_amdgcn_mfma_f32_16x16x32_bf16(fa[mi][kk], fb1[ni][kk],
                                                                    acc[mi][ni + 2], 0, 0, 0);
    __builtin_amdgcn_s_setprio(0);
    // P3: A upper half -> quadrant (4-7, 0-1)
#pragma unroll
    for (int mi = 0; mi < 4; mi++)
#pragma unroll
      for (int kk = 0; kk < 2; kk++) fa[mi][kk] = rdA(bb, mi + 4, kk);
    __builtin_amdgcn_s_setprio(1);
#pragma unroll
    for (int mi = 0; mi < 4; mi++)
#pragma unroll
      for (int ni = 0; ni < 2; ni++)
#pragma unroll
        for (int kk = 0; kk < 2; kk++)
          acc[mi + 4][ni] = __builtin_amdgcn_mfma_f32_16x16x32_bf16(fa[mi][kk], fb0[ni][kk],
                                                                    acc[mi + 4][ni], 0, 0, 0);
    __builtin_amdgcn_s_setprio(0);
    // P4: quadrant (4-7, 2-3)
    __builtin_amdgcn_s_setprio(1);
#pragma unroll
    for (int mi = 0; mi < 4; mi++)
#pragma unroll
      for (int ni = 0; ni < 2; ni++)
#pragma unroll
        for (int kk = 0; kk < 2; kk++)
          acc[mi + 4][ni + 2] = __builtin_amdgcn_mfma_f32_16x16x32_bf16(fa[mi][kk], fb1[ni][kk],
                                                                        acc[mi + 4][ni + 2], 0, 0, 0);
    __builtin_amdgcn_s_setprio(0);

    __builtin_amdgcn_s_barrier();  // all waves done reading buf bb
    __builtin_amdgcn_sched_barrier(0);
    if (kt + 2 < nkt) stage(kt + 2, bb);
  }

  // epilogue: C/D layout col=lane&15, row=(lane>>4)*4+reg (m89-verified)
  const int l15 = l & 15, lg4 = l >> 4;
  int outbf = 1;
  if constexpr (EPI == 5) outbf = a.dflag[0];
#pragma unroll
  for (int mi = 0; mi < 8; mi++) {
#pragma unroll
    for (int j = 0; j < 4; j++) {
      int crow = m0 + wm * 128 + mi * 16 + lg4 * 4 + j;
#pragma unroll
      for (int ni = 0; ni < 4; ni++) {
        int n = n0 + wn * 64 + ni * 16 + l15;
        float v = acc[mi][ni][j];
        if constexpr (EPI == 6) {
          float g = a.gates[(long)crow * 4 + (n >> 10)];
          v = g * fmaxf(v + a.bias[n], 0.f);
          ((bf16*)a.C)[(long)crow * a.ldc + n] = tob(v);
        } else if constexpr (EPI == 7) {
          const float* gr = a.gates + (long)crow * 4;
          v += gr[0] * a.bias[n] + gr[1] * a.bias[512 + n] + gr[2] * a.bias[1024 + n] +
               gr[3] * a.bias[1536 + n];
          ((bf16*)a.C)[(long)crow * a.ldc + n] = tob(v);
        } else if constexpr (EPI == 8) {
          ((bf16*)a.C)[(long)crow * a.ldc + n] = tob(v);
        } else if constexpr (EPI == 5) {
          float o = tof(a.P1[(long)crow * a.N + n]) + a.wsel[crow] * v + a.bias[n];
          if (outbf) ((bf16*)a.C)[(long)crow * a.ldc + n] = tob(o);
          else ((float*)a.C)[(long)crow * a.ldc + n] = o;
        }
      }
    }
  }
}

// =====================  small kernels  =====================
__global__ __launch_bounds__(256) void gates_k(const bf16* x, const float* gw, const float* gb,
                                               float* gates) {
  int b = blockIdx.x * 4 + (threadIdx.x >> 6);
  int l = threadIdx.x & 63;
  short8 xv = *(const short8*)(x + (long)b * cD + l * 8);
  float a0 = 0, a1 = 0, a2 = 0, a3 = 0;
#pragma unroll
  for (int j = 0; j < 8; j++) {
    float xf = b2f(xv[j]);
    f32x4 wr = *(const f32x4*)(gw + (l * 8 + j) * 4);
    a0 += xf * wr[0];
    a1 += xf * wr[1];
    a2 += xf * wr[2];
    a3 += xf * wr[3];
  }
#pragma unroll
  for (int o = 32; o > 0; o >>= 1) {
    a0 += __shfl_xor(a0, o);
    a1 += __shfl_xor(a1, o);
    a2 += __shfl_xor(a2, o);
    a3 += __shfl_xor(a3, o);
  }
  a0 += gb[0];
  a1 += gb[1];
  a2 += gb[2];
  a3 += gb[3];
  float m = fmaxf(fmaxf(a0, a1), fmaxf(a2, a3));
  float e0 = expf(a0 - m), e1 = expf(a1 - m), e2 = expf(a2 - m), e3 = expf(a3 - m);
  float s = e0 + e1 + e2 + e3;
  if (l == 0) {
    float* gp = gates + (long)b * 4;
    gp[0] = e0 / s;
    gp[1] = e1 / s;
    gp[2] = e2 / s;
    gp[3] = e3 / s;
  }
}

__global__ __launch_bounds__(256) void bhist_k(const int* sid, int* bh) {
  int blk = blockIdx.x, t = threadIdx.x;
  __shared__ int h[cS];
  if (t < cS) h[t] = 0;
  __syncthreads();
  int s = sid[blk * 256 + t];
#pragma unroll
  for (int q = 0; q < cS; q++) {
    unsigned long long m = __ballot(s == q);
    if ((t & 63) == 0) atomicAdd(&h[q], __popcll(m));
  }
  __syncthreads();
  if (t < cS) bh[blk * cS + t] = h[t];
}

__global__ void bbase_k(const int* bh, int* base, int* cum) {
  __shared__ int tot[cS];
  int s = threadIdx.x;
  if (s < cS) {
    int run = 0;
    for (int b = 0; b < 64; b++) {
      base[b * cS + s] = run;
      run += bh[b * cS + s];
    }
    tot[s] = run;
  }
  __syncthreads();
  if (s == 0) {
    int run = 0;
    for (int q = 0; q < cS; q++) {
      cum[q] = run;
      run += tot[q];
    }
    cum[cS] = run;
  }
  __syncthreads();
  if (s < cS) {
    int c = cum[s];
    for (int b = 0; b < 64; b++) base[b * cS + s] += c;
  }
}

__global__ __launch_bounds__(256) void bscat_k(const int* sid, const int* base, int* perm) {
  int blk = blockIdx.x, t = threadIdx.x, w = t >> 6, l = t & 63;
  __shared__ int wc[4][cS];
  __shared__ int wb[4][cS];
  int s = sid[blk * 256 + t];
  int rank = 0;
#pragma unroll
  for (int q = 0; q < cS; q++) {
    unsigned long long m = __ballot(s == q);
    if (l == 0) wc[w][q] = __popcll(m);
    if (s == q) rank = __popcll(m & ((1ull << l) - 1ull));
  }
  __syncthreads();
  if (t < cS) {
    int run = 0;
#pragma unroll
    for (int ww = 0; ww < 4; ww++) {
      wb[ww][t] = run;
      run += wc[ww][t];
    }
  }
  __syncthreads();
  perm[base[blk * cS + s] + wb[w][s] + rank] = blk * 256 + t;
}

__global__ __launch_bounds__(256) void scenpart_k(const float* emb, const float* w1,
                                                  const float* b1, float* scp) {
  __shared__ float red[8][32];
  int s = blockIdx.x;
  int nl = threadIdx.x & 31;
  int n = blockIdx.y * 32 + nl;
  int dg = threadIdx.x >> 5;
  float a = 0.f;
#pragma unroll 4
  for (int d = dg * 64; d < dg * 64 + 64; d++) a += emb[s * cD + d] * w1[(long)(cD + d) * cDH + n];
  red[dg][nl] = a;
  __syncthreads();
  if (dg == 0) {
    float t = b1[n];
#pragma unroll
    for (int g = 0; g < 8; g++) t += red[g][nl];
    scp[s * cDH + n] = t;
  }
}

__global__ __launch_bounds__(256) void wsel_k(const float* sp, const float* scp, const float* w2,
                                              const int* sid, float* wsel) {
  int b = blockIdx.x * 4 + (threadIdx.x >> 6);
  int l = threadIdx.x & 63;
  float spv[4], w2v[4];
#pragma unroll
  for (int q = 0; q < 4; q++) {
    spv[q] = sp[(long)b * cDH + q * 64 + l];
    w2v[q] = w2[q * 64 + l];
  }
  float lg[8];
#pragma unroll
  for (int s = 0; s < 8; s++) {
    float acc = 0.f;
#pragma unroll
    for (int q = 0; q < 4; q++) {
      float v = spv[q] + scp[s * cDH + q * 64 + l];
      v = fmaxf(v, 0.f);
      acc += v * w2v[q];
    }
#pragma unroll
    for (int o = 32; o > 0; o >>= 1) acc += __shfl_xor(acc, o);
    lg[s] = acc;
  }
  float m = lg[0];
#pragma unroll
  for (int s = 1; s < 8; s++) m = fmaxf(m, lg[s]);
  float sum = 0.f;
#pragma unroll
  for (int s = 0; s < 8; s++) sum += expf(lg[s] - m);
  if (l == 0) {
    int s0 = sid[b];
    wsel[b] = expf(lg[s0] - m) / sum;
  }
}

__global__ __launch_bounds__(256) void cvt_shared_k(const float* sf, bf16* ss) {
  int i = blockIdx.x * 256 + threadIdx.x;
  int r = i >> 7, c = (i & 127) * 4;
  f32x4 v = *(const f32x4*)(sf + (long)r * cD + c);
  short4v o;
#pragma unroll
  for (int j = 0; j < 4; j++) o[j] = __builtin_bit_cast(short, tob(v[j]));
  *(short4v*)(ss + (long)r * 1024 + c) = o;
}

// =====================  launcher  =====================
extern "C" void kernel_launch(void* const* d_in, const int* in_sizes, int n_in, void* d_out,
                              int out_size, void* d_ws, size_t ws_size, hipStream_t stream) {
  const void* x = d_in[0];
  const int* sid = (const int*)d_in[1];

  char* ws = (char*)d_ws;
  size_t off = 0;
  auto alloc = [&](size_t bytes) -> void* {
    void* p = ws + off;
    off += (bytes + 255) & ~(size_t)255;
    return p;
  };
  int* g_flag = (int*)alloc(64);
  float* g_gates = (float*)alloc((size_t)cB * 4 * 4);
  float* g_wsel = (float*)alloc((size_t)cB * 4);
  int* g_perm = (int*)alloc((size_t)cB * 4);
  int* g_bh = (int*)alloc(64 * cS * 4);
  int* g_base = (int*)alloc(64 * cS * 4);
  int* g_cum = (int*)alloc(64);
  float* g_scp = (float*)alloc((size_t)cS * cDH * 4);
  float* g_small = (float*)alloc((size_t)300000 * 4);
  bf16* g_xb = (bf16*)alloc((size_t)cB * cD * 2);
  bf16* w1t = (bf16*)alloc((size_t)cE * cH * cD * 2);
  bf16* w2cat = (bf16*)alloc((size_t)cD * 4096 * 2);
  bf16* s1t = (bf16*)alloc((size_t)cS * cH * cD * 2);
  bf16* s2t = (bf16*)alloc((size_t)cS * cD * cH * 2);
  bf16* a1t = (bf16*)alloc((size_t)cDH * cD * 2);
  bf16* ow1t = (bf16*)alloc((size_t)cD * 1024 * 2);
  bf16* ow2t = (bf16*)alloc((size_t)cD * 1024 * 2);
  bf16* g_ss = (bf16*)alloc((size_t)cB * 1024 * 2);
  size_t fixed_end = off;
  const size_t MB = 1024ull * 1024ull;
  const bool BIG = (ws_size == 0) || (fixed_end + 135 * MB <= ws_size);
  char* g_big = (char*)alloc(BIG ? 135 * MB : 85 * MB);
  (void)in_sizes;
  (void)n_in;
  (void)out_size;

  // opt-in to 128KB dynamic LDS for the 256^2 engine; fall back if refused
  bool use256 = true;
  use256 &= hipFuncSetAttribute(reinterpret_cast<const void*>(gemm256_k<6>),
                                hipFuncAttributeMaxDynamicSharedMemorySize, 131072) == hipSuccess;
  use256 &= hipFuncSetAttribute(reinterpret_cast<const void*>(gemm256_k<7>),
                                hipFuncAttributeMaxDynamicSharedMemorySize, 131072) == hipSuccess;
  use256 &= hipFuncSetAttribute(reinterpret_cast<const void*>(gemm256_k<8>),
                                hipFuncAttributeMaxDynamicSharedMemorySize, 131072) == hipSuccess;
  use256 &= hipFuncSetAttribute(reinterpret_cast<const void*>(gemm256_k<5>),
                                hipFuncAttributeMaxDynamicSharedMemorySize, 131072) == hipSuccess;

  dim3 blk(256);
  probe_k<<<1, blk, 0, stream>>>(x, g_flag);
  cvtx_k<<<cB * cD / 8 / 256, blk, 0, stream>>>(x, g_xb, g_flag);

  const int O_GW = 0, O_GB = 2048, O_SB1 = 2052, O_SB2 = 6148, O_PB1 = 8196, O_PB2 = 16388,
            O_EMB = 20484, O_AW1 = 24580, O_AB1 = 286724, O_AW2 = 286980, O_OB = 287236,
            O_END = 287748;
  {
    CvtDesc d;
    const void* srcs[11] = {d_in[2],  d_in[3],  d_in[5],  d_in[7],  d_in[9], d_in[11],
                            d_in[12], d_in[13], d_in[14], d_in[15], d_in[18]};
    int offs[12] = {O_GW, O_GB, O_SB1, O_SB2, O_PB1, O_PB2, O_EMB, O_AW1, O_AB1, O_AW2, O_OB,
                    O_END};
    for (int i = 0; i < 11; i++) d.src[i] = srcs[i];
    for (int i = 0; i < 12; i++) d.off[i] = offs[i];
    cvt_smalls_k<<<(O_END + 255) / 256, blk, 0, stream>>>(d, g_flag, g_small);
  }

  transpose_k<<<dim3(cH / 32, cD / 32, cE), blk, 0, stream>>>(d_in[4], w1t, cH, cD, 0,
                                                              (long)cD * cH, (long)cH * cD, g_flag);
  transpose_k<<<dim3(cD / 32, cH / 32, cE), blk, 0, stream>>>(d_in[6], w2cat, cD, 4096, 0,
                                                              (long)cH * cD, 1024, g_flag);
  transpose_k<<<dim3(cH / 32, cD / 32, cS), blk, 0, stream>>>(d_in[8], s1t, cH, cD, 0,
                                                              (long)cD * cH, (long)cH * cD, g_flag);
  transpose_k<<<dim3(cD / 32, cH / 32, cS), blk, 0, stream>>>(d_in[10], s2t, cD, cH, 0,
                                                              (long)cH * cD, (long)cD * cH, g_flag);
  transpose_k<<<dim3(cDH / 32, cD / 32, 1), blk, 0, stream>>>(d_in[13], a1t, cDH, cD, 0, 0, 0,
                                                              g_flag);
  transpose_k<<<dim3(cD / 32, cD / 32, 1), blk, 0, stream>>>(d_in[17], ow1t, cD, 1024, 0, 0, 0,
                                                             g_flag);
  transpose_k<<<dim3(cD / 32, cD / 32, 1), blk, 0, stream>>>(d_in[17], ow1t + 512, cD, 1024,
                                                             (long)1024 * cD, 0, 0, g_flag);
  transpose_k<<<dim3(cD / 32, cD / 32, 1), blk, 0, stream>>>(d_in[17], ow2t, cD, 1024,
                                                             (long)512 * cD, 0, 0, g_flag);
  transpose_k<<<dim3(cD / 32, cD / 32, 1), blk, 0, stream>>>(d_in[17], ow2t + 512, cD, 1024,
                                                             (long)1536 * cD, 0, 0, g_flag);

  gates_k<<<cB / 4, blk, 0, stream>>>(g_xb, g_small + O_GW, g_small + O_GB, g_gates);
  bhist_k<<<cB / 256, blk, 0, stream>>>(sid, g_bh);
  bbase_k<<<1, 64, 0, stream>>>(g_bh, g_base, g_cum);
  bscat_k<<<cB / 256, blk, 0, stream>>>(sid, g_base, g_perm);

  if (BIG) {
    bf16* h4 = (bf16*)g_big;              // [16384,4096]
    float* sp = (float*)g_big;            // [16384,256] (after h4 dead)
    bf16* hspec = (bf16*)g_big;           // [16384,1024] (after sp dead)
    bf16* P1 = (bf16*)(g_big + 34 * MB);  // [16384,512] bf16

    if (use256) {
      G6Args a{};
      a.A = g_xb; a.Bt = w1t; a.C = h4;
      a.N = 4096; a.K = cD; a.ldc = 4096;
      a.bias = g_small + O_SB1; a.gates = g_gates;
      gemm256_k<6><<<dim3(16, 64), 512, 131072, stream>>>(a);
    } else {
      GArgs a{};
      a.A = g_xb; a.lda = cD; a.Bt = w1t; a.ldb = cD;
      a.C = h4; a.ldc = 4096; a.M = cB; a.N = 4096; a.K = cD;
      a.bias = g_small + O_SB1; a.gates = g_gates;
      gemm_k<6, false, false, false><<<dim3(32, cB / 128), blk, 0, stream>>>(a);
    }
    if (use256) {
      G6Args a{};
      a.A = h4; a.Bt = w2cat; a.C = g_ss;
      a.N = cD; a.K = 4096; a.ldc = 1024;
      a.bias = g_small + O_SB2; a.gates = g_gates;
      gemm256_k<7><<<dim3(2, 64), 512, 131072, stream>>>(a);
    } else {
      GArgs a{};
      a.A = h4; a.lda = 4096; a.Bt = w2cat; a.ldb = 4096;
      a.C = g_ss; a.ldc = 1024; a.M = cB; a.N = cD; a.K = 4096;
      a.bias = g_small + O_SB2; a.gates = g_gates;
      gemm_k<7, false, false, false><<<dim3(cD / 128, cB / 128), blk, 0, stream>>>(a);
    }
    {
      GArgs a{};
      a.A = g_ss; a.lda = 1024; a.Bt = a1t; a.ldb = cD;
      a.C = sp; a.ldc = cDH; a.M = cB; a.N = cDH; a.K = cD;
      gemm_k<3, false, false, false><<<dim3(cDH / 128, cB / 128), blk, 0, stream>>>(a);
    }
    scenpart_k<<<dim3(cS, 8), blk, 0, stream>>>(g_small + O_EMB, g_small + O_AW1, g_small + O_AB1,
                                                g_scp);
    wsel_k<<<cB / 4, blk, 0, stream>>>(sp, g_scp, g_small + O_AW2, sid, g_wsel);
    {
      GArgs a{};
      a.A = g_xb; a.lda = cD; a.Bt = s1t; a.ldb = cD; a.bt_stride = (long)cH * cD;
      a.C = hspec; a.ldc = cH; a.M = cB; a.N = cH; a.K = cD;
      a.bias = g_small + O_PB1; a.bias_stride = cH;
      a.perm = g_perm; a.cum = g_cum;
      gemm_k<1, true, true, false><<<dim3(cH / 128, cB / 128, cS), blk, 0, stream>>>(a);
    }
    {
      GArgs a{};
      a.A = hspec; a.lda = cH; a.Bt = s2t; a.ldb = cH; a.bt_stride = (long)cD * cH;
      a.C = g_ss + 512; a.ldc = 1024; a.M = cB; a.N = cD; a.K = cH;
      a.bias = g_small + O_PB2; a.bias_stride = cD;
      a.perm = g_perm; a.cum = g_cum;
      gemm_k<4, true, false, true><<<dim3(cD / 128, cB / 128, cS), blk, 0, stream>>>(a);
    }
    if (use256) {
      G6Args a{};
      a.A = g_ss; a.Bt = ow1t; a.C = P1;
      a.N = cD; a.K = 1024; a.ldc = cD;
      gemm256_k<8><<<dim3(2, 64), 512, 131072, stream>>>(a);
    } else {
      GArgs a{};
      a.A = g_ss; a.lda = 1024; a.Bt = ow1t; a.ldb = 1024;
      a.C = P1; a.ldc = cD; a.M = cB; a.N = cD; a.K = 1024;
      gemm_k<8, false, false, false><<<dim3(cD / 128, cB / 128), blk, 0, stream>>>(a);
    }
    if (use256) {
      G6Args a{};
      a.A = g_ss; a.Bt = ow2t; a.C = d_out;
      a.N = cD; a.K = 1024; a.ldc = cD;
      a.bias = g_small + O_OB; a.P1 = P1; a.wsel = g_wsel; a.dflag = g_flag;
      gemm256_k<5><<<dim3(2, 64), 512, 131072, stream>>>(a);
    } else {
      GArgs a{};
      a.A = g_ss; a.lda = 1024; a.Bt = ow2t; a.ldb = 1024;
      a.C = d_out; a.ldc = cD; a.M = cB; a.N = cD; a.K = 1024;
      a.bias = g_small + O_OB; a.P1 = P1; a.wsel = g_wsel; a.dflag = g_flag;
      gemm_k<5, false, false, false><<<dim3(cD / 128, cB / 128), blk, 0, stream>>>(a);
    }
  } else {
    // fallback: sequential-expert structure inside 85MB scratch
    float* f32a = (float*)g_big;
    bf16* hbuf = (bf16*)(g_big + 34 * MB);
    bf16* P1b = (bf16*)(g_big + 68 * MB);
    for (int e = 0; e < cE; e++) {
      GArgs a1{};
      a1.A = g_xb; a1.lda = cD; a1.Bt = w1t + (size_t)e * cH * cD; a1.ldb = cD;
      a1.C = hbuf; a1.ldc = cH; a1.M = cB; a1.N = cH; a1.K = cD;
      a1.bias = g_small + O_SB1 + e * cH;
      gemm_k<1, false, false, false><<<dim3(cH / 128, cB / 128), blk, 0, stream>>>(a1);
      GArgs a2{};
      a2.A = hbuf; a2.lda = cH; a2.Bt = w2cat + (size_t)e * 1024; a2.ldb = 4096;
      a2.C = f32a; a2.ldc = cD; a2.M = cB; a2.N = cD; a2.K = cH;
      a2.bias = g_small + O_SB2 + e * cD; a2.gates = g_gates; a2.eidx = e;
      gemm_k<2, false, false, false><<<dim3(cD / 128, cB / 128), blk, 0, stream>>>(a2);
    }
    cvt_shared_k<<<cB * 128 / 256, blk, 0, stream>>>(f32a, g_ss);
    {
      GArgs a{};
      a.A = g_xb; a.lda = cD; a.Bt = s1t; a.ldb = cD; a.bt_stride = (long)cH * cD;
      a.C = hbuf; a.ldc = cH; a.M = cB; a.N = cH; a.K = cD;
      a.bias = g_small + O_PB1; a.bias_stride = cH;
      a.perm = g_perm; a.cum = g_cum;
      gemm_k<1, true, true, false><<<dim3(cH / 128, cB / 128, cS), blk, 0, stream>>>(a);
    }
    {
      GArgs a{};
      a.A = hbuf; a.lda = cH; a.Bt = s2t; a.ldb = cH; a.bt_stride = (long)cD * cH;
      a.C = g_ss + 512; a.ldc = 1024; a.M = cB; a.N = cD; a.K = cH;
      a.bias = g_small + O_PB2; a.bias_stride = cD;
      a.perm = g_perm; a.cum = g_cum;
      gemm_k<4, true, false, true><<<dim3(cD / 128, cB / 128, cS), blk, 0, stream>>>(a);
    }
    {
      GArgs a{};
      a.A = g_ss; a.lda = 1024; a.Bt = a1t; a.ldb = cD;
      a.C = f32a; a.ldc = cDH; a.M = cB; a.N = cDH; a.K = cD;
      gemm_k<3, false, false, false><<<dim3(cDH / 128, cB / 128), blk, 0, stream>>>(a);
    }
    scenpart_k<<<dim3(cS, 8), blk, 0, stream>>>(g_small + O_EMB, g_small + O_AW1, g_small + O_AB1,
                                                g_scp);
    wsel_k<<<cB / 4, blk, 0, stream>>>(f32a, g_scp, g_small + O_AW2, sid, g_wsel);
    {
      GArgs a{};
      a.A = g_ss; a.lda = 1024; a.Bt = ow1t; a.ldb = 1024;
      a.C = P1b; a.ldc = cD; a.M = cB; a.N = cD; a.K = 1024;
      gemm_k<8, false, false, false><<<dim3(cD / 128, cB / 128), blk, 0, stream>>>(a);
    }
    {
      GArgs a{};
      a.A = g_ss; a.lda = 1024; a.Bt = ow2t; a.ldb = 1024;
      a.C = d_out; a.ldc = cD; a.M = cB; a.N = cD; a.K = 1024;
      a.bias = g_small + O_OB; a.P1 = P1b; a.wsel = g_wsel; a.dflag = g_flag;
      gemm_k<5, false, false, false><<<dim3(cD / 128, cB / 128), blk, 0, stream>>>(a);
    }
  }
}

// Round 7
// 412.457 us; speedup vs baseline: 1.3906x; 1.3906x over previous
//
#include <hip/hip_runtime.h>
#include <hip/hip_bf16.h>
#include <stdint.h>

typedef __hip_bfloat16 bf16;
typedef __attribute__((ext_vector_type(8))) short short8;
typedef __attribute__((ext_vector_type(4))) short short4v;
typedef __attribute__((ext_vector_type(4))) float f32x4;

constexpr int cB = 16384, cD = 512, cH = 1024, cS = 8, cE = 4, cDH = 256;

__device__ __forceinline__ float tof(bf16 v) { return __bfloat162float(v); }
__device__ __forceinline__ bf16 tob(float v) { return __float2bfloat16(v); }
__device__ __forceinline__ float b2f(short s) {
  uint32_t u = ((uint32_t)(uint16_t)s) << 16;
  return __builtin_bit_cast(float, u);
}
__device__ __forceinline__ float ldf(const void* p, long i, int isbf) {
  return isbf ? b2f(((const short*)p)[i]) : ((const float*)p)[i];
}
__device__ __forceinline__ void stbf_nt(bf16* p, float v) {
  __builtin_nontemporal_store(__builtin_bit_cast(short, tob(v)), (short*)p);
}

__device__ __forceinline__ void gload_lds16(const bf16* g, char* l) {
  __builtin_amdgcn_global_load_lds(
      (const __attribute__((address_space(1))) void*)g,
      (__attribute__((address_space(3))) void*)l, 16, 0, 0);
}

// ---- dtype probe ----
__global__ __launch_bounds__(256) void probe_k(const void* x, int* flag) {
  __shared__ int sh[256];
  const unsigned short* u = (const unsigned short*)x;
  int cnt = 0;
  for (int i = threadIdx.x; i < 2048; i += 256) {
    float v = fabsf(b2f((short)u[2 * i]));
    cnt += (v > 1e-5f && v < 1e3f) ? 1 : 0;
  }
  sh[threadIdx.x] = cnt;
  __syncthreads();
  for (int s = 128; s > 0; s >>= 1) {
    if (threadIdx.x < s) sh[threadIdx.x] += sh[threadIdx.x + s];
    __syncthreads();
  }
  if (threadIdx.x == 0) flag[0] = (sh[0] > 1024) ? 1 : 0;
}

__global__ __launch_bounds__(256) void cvtx_k(const void* x, bf16* xb, const int* flag) {
  int g = blockIdx.x * 256 + threadIdx.x;
  if (flag[0]) {
    ((short8*)xb)[g] = ((const short8*)x)[g];
  } else {
    const f32x4* xf = (const f32x4*)x;
    f32x4 v0 = xf[2 * g], v1 = xf[2 * g + 1];
    short8 o;
#pragma unroll
    for (int j = 0; j < 4; j++) {
      o[j] = __builtin_bit_cast(short, tob(v0[j]));
      o[j + 4] = __builtin_bit_cast(short, tob(v1[j]));
    }
    ((short8*)xb)[g] = o;
  }
}

struct CvtDesc {
  const void* src[11];
  int off[12];
};
__global__ __launch_bounds__(256) void cvt_smalls_k(CvtDesc d, const int* flag, float* dst) {
  int i = blockIdx.x * 256 + threadIdx.x;
  if (i >= d.off[11]) return;
  int isb = flag[0];
  int j = 0;
  while (i >= d.off[j + 1]) j++;
  dst[i] = ldf(d.src[j], i - d.off[j], isb);
}

__global__ __launch_bounds__(256) void transpose_k(const void* in, bf16* out, int ldin, int ldout,
                                                   long in_off, long in_bs, long out_bs,
                                                   const int* flag) {
  __shared__ float tile[32][33];
  int isb = flag[0];
  long src0 = in_off + (long)blockIdx.z * in_bs;
  bf16* dst = out + (long)blockIdx.z * out_bs;
  int c0 = blockIdx.x * 32, r0 = blockIdx.y * 32;
  int tx = threadIdx.x & 31, ty = threadIdx.x >> 5;
#pragma unroll
  for (int i = 0; i < 4; i++)
    tile[ty + i * 8][tx] = ldf(in, src0 + (long)(r0 + ty + i * 8) * ldin + c0 + tx, isb);
  __syncthreads();
#pragma unroll
  for (int i = 0; i < 4; i++)
    dst[(long)(c0 + ty + i * 8) * ldout + r0 + tx] = tob(tile[tx][ty + i * 8]);
}

// ---- out_w -> owpair: interleaved [W0;W2]^T / [W1;W3]^T rows so one GEMM
// block holds both matrices at the same output column (EPI9 pairing).
// owpair row for out col n, matrix m: R = (n>>6)*128 + ((n>>5)&1)*64 + m*32 +
// ((n>>4)&1)*16 + (n&15). quadrant z of out_w: rows z*512.., matrix m=z&1
// (W0,W2->m0; W1,W3->m1), k-offset (z>>1)*512... careful: quadrant order is
// W0(z=0,m0,k0), W1(z=1,m1,k0), W2(z=2,m0,k512), W3(z=3,m1,k512).
__global__ __launch_bounds__(256) void owt_k(const void* ow, bf16* owpair, const int* flag) {
  __shared__ float tile[32][33];
  int isb = flag[0];
  int z = blockIdx.z;
  int m = z & 1, kb = (z >> 1) * 512;
  long base = (long)z * 512 * cD;
  int c0 = blockIdx.x * 32, r0 = blockIdx.y * 32;  // c = n (col of quadrant), r = k
  int tx = threadIdx.x & 31, ty = threadIdx.x >> 5;
#pragma unroll
  for (int i = 0; i < 4; i++)
    tile[ty + i * 8][tx] = ldf(ow, base + (long)(r0 + ty + i * 8) * cD + c0 + tx, isb);
  __syncthreads();
#pragma unroll
  for (int i = 0; i < 4; i++) {
    int n = c0 + ty + i * 8;
    int R = ((n >> 6) << 7) + (((n >> 5) & 1) << 6) + (m << 5) + (((n >> 4) & 1) << 4) + (n & 15);
    owpair[(long)R * 1024 + kb + r0 + tx] = tob(tile[tx][ty + i * 8]);
  }
}

// ================  128x128 GEMM engine (proven r2-r5)  ================
// EPI: 1 relu(acc+bias)->bf16 [nt-store] ; 2 C(f32) (=/+=) gates*(acc+bias)
//      3 C(f32)=acc ; 4 (acc+bias)->bf16 ; 6 gates[b,n>>10]*relu(acc+bias)->bf16 [nt]
//      7 acc + gates[b,:]·b2[:,n] -> bf16 ; 9 merged: acc1 + wsel*acc2 + bias -> out
struct GArgs {
  const bf16* A; int lda;
  const bf16* Bt; int ldb; long bt_stride;
  void* C; int ldc;
  int M, N, K;
  const float* bias; int bias_stride;
  const float* gates; int eidx;
  const int* perm; const int* cum;
  const float* wsel;
  const int* dflag;
};

template <int EPI, bool GROUPED, bool GATHER_A, bool SCATTER_C>
__global__ __launch_bounds__(256, 4) void gemm_k(GArgs a) {
  __shared__ char smem[32768];
  char* ldsA = smem;
  char* ldsB = smem + 16384;

  int bxs, bys;
  if constexpr (!GROUPED) {
    // XCD-aware bijective remap (T1/m204); grouped kernels keep identity
    // (early-exit would concentrate live blocks on XCD0 — r4 post-mortem).
    const int gx = gridDim.x;
    const int nwg = gx * gridDim.y;
    const int d = blockIdx.y * gx + blockIdx.x;
    const int q = nwg >> 3, r = nwg & 7;
    const int xcd = d & 7, di = d >> 3;
    const int logical = (xcd < r ? xcd * (q + 1) : r * (q + 1) + (xcd - r) * q) + di;
    bxs = logical % gx;
    bys = logical / gx;
  } else {
    bxs = blockIdx.x;
    bys = blockIdx.y;
  }

  int g0, cnt;
  if constexpr (GROUPED) {
    int z = blockIdx.z;
    g0 = a.cum[z];
    cnt = a.cum[z + 1] - g0;
  } else {
    g0 = 0;
    cnt = a.M;
  }
  const int ptile = bys * 128;
  if (ptile >= cnt) return;
  const int n0 = bxs * 128;

  const int t = threadIdx.x, w = t >> 6, l = t & 63;
  const int wm = w >> 1, wn = w & 1;

  const bf16* bt = a.Bt + (GROUPED ? (long)blockIdx.z * a.bt_stride : 0);
  const float* bias = a.bias ? (a.bias + (GROUPED ? blockIdx.z * a.bias_stride : 0)) : nullptr;

  const bf16* aSrc[4];
  const bf16* bSrc[4];
  int ldsOff[4];
#pragma unroll
  for (int c = 0; c < 4; c++) {
    int pos = w * 4096 + c * 1024 + l * 16;
    int row = pos >> 7;
    int su = ((((pos >> 4) & 7) ^ (row & 7))) * 8;
    int p = ptile + row;
    if (p > cnt - 1) p = cnt - 1;
    int ar;
    if constexpr (GATHER_A) ar = a.perm[g0 + p];
    else ar = g0 + p;
    aSrc[c] = a.A + (long)ar * a.lda + su;
    bSrc[c] = bt + (long)(n0 + row) * a.ldb + su;
    ldsOff[c] = w * 4096 + c * 1024;
  }

  f32x4 zero = {0.f, 0.f, 0.f, 0.f};
  f32x4 acc[4][4];
#pragma unroll
  for (int i = 0; i < 4; i++)
#pragma unroll
    for (int j = 0; j < 4; j++) acc[i][j] = zero;

  const int nkt = a.K >> 6;
  for (int kt = 0; kt < nkt; ++kt) {
#pragma unroll
    for (int c = 0; c < 4; c++) gload_lds16(aSrc[c] + kt * 64, ldsA + ldsOff[c]);
#pragma unroll
    for (int c = 0; c < 4; c++) gload_lds16(bSrc[c] + kt * 64, ldsB + ldsOff[c]);
    __syncthreads();
#pragma unroll
    for (int kk = 0; kk < 2; kk++) {
      short8 af[4], bv[4];
#pragma unroll
      for (int mi = 0; mi < 4; mi++) {
        int row = wm * 64 + mi * 16 + (l & 15);
        int kg = kk * 4 + (l >> 4);
        int off = row * 128 + ((kg ^ (row & 7)) << 4);
        af[mi] = *(const short8*)(ldsA + off);
      }
#pragma unroll
      for (int ni = 0; ni < 4; ni++) {
        int row = wn * 64 + ni * 16 + (l & 15);
        int kg = kk * 4 + (l >> 4);
        int off = row * 128 + ((kg ^ (row & 7)) << 4);
        bv[ni] = *(const short8*)(ldsB + off);
      }
#pragma unroll
      for (int mi = 0; mi < 4; mi++)
#pragma unroll
        for (int ni = 0; ni < 4; ni++)
          acc[mi][ni] =
              __builtin_amdgcn_mfma_f32_16x16x32_bf16(af[mi], bv[ni], acc[mi][ni], 0, 0, 0);
    }
    __syncthreads();
  }

  const int l15 = l & 15, lg4 = l >> 4;
  int outbf = 1;
  if constexpr (EPI == 9) outbf = a.dflag[0];
#pragma unroll
  for (int mi = 0; mi < 4; mi++) {
#pragma unroll
    for (int j = 0; j < 4; j++) {
      int p = ptile + wm * 64 + mi * 16 + lg4 * 4 + j;
      if (p >= cnt) continue;
      int crow;
      if constexpr (SCATTER_C) crow = a.perm[g0 + p];
      else crow = g0 + p;
      if constexpr (EPI == 9) {
        // merged P1+out: ni pairs (0,2) and (1,3) share the output column
        float wv = a.wsel[crow];
#pragma unroll
        for (int ni = 0; ni < 2; ni++) {
          int n = (n0 >> 1) + wn * 32 + ni * 16 + l15;
          float o = acc[mi][ni][j] + wv * acc[mi][ni + 2][j] + a.bias[n];
          if (outbf) ((bf16*)a.C)[(long)crow * a.ldc + n] = tob(o);
          else ((float*)a.C)[(long)crow * a.ldc + n] = o;
        }
        continue;
      }
#pragma unroll
      for (int ni = 0; ni < 4; ni++) {
        int n = n0 + wn * 64 + ni * 16 + l15;
        float v = acc[mi][ni][j];
        if constexpr (EPI == 1) {
          v += bias[n];
          v = fmaxf(v, 0.f);
          stbf_nt(&((bf16*)a.C)[(long)crow * a.ldc + n], v);
        } else if constexpr (EPI == 2) {
          float g = a.gates[(long)(g0 + p) * 4 + a.eidx];
          v = g * (v + bias[n]);
          float* Cf = (float*)a.C;
          long idx = (long)crow * a.ldc + n;
          if (a.eidx == 0) Cf[idx] = v;
          else Cf[idx] += v;
        } else if constexpr (EPI == 3) {
          ((float*)a.C)[(long)crow * a.ldc + n] = v;
        } else if constexpr (EPI == 4) {
          v += bias[n];
          ((bf16*)a.C)[(long)crow * a.ldc + n] = tob(v);
        } else if constexpr (EPI == 6) {
          float g = a.gates[(long)(g0 + p) * 4 + (n >> 10)];
          v = g * fmaxf(v + bias[n], 0.f);
          stbf_nt(&((bf16*)a.C)[(long)crow * a.ldc + n], v);
        } else if constexpr (EPI == 7) {
          const float* gr = a.gates + (long)(g0 + p) * 4;
          v += gr[0] * bias[n] + gr[1] * bias[512 + n] + gr[2] * bias[1024 + n] +
               gr[3] * bias[1536 + n];
          ((bf16*)a.C)[(long)crow * a.ldc + n] = tob(v);
        }
      }
    }
  }
}

// =====================  small kernels  =====================
__global__ __launch_bounds__(256) void gates_k(const bf16* x, const float* gw, const float* gb,
                                               float* gates) {
  int b = blockIdx.x * 4 + (threadIdx.x >> 6);
  int l = threadIdx.x & 63;
  short8 xv = *(const short8*)(x + (long)b * cD + l * 8);
  float a0 = 0, a1 = 0, a2 = 0, a3 = 0;
#pragma unroll
  for (int j = 0; j < 8; j++) {
    float xf = b2f(xv[j]);
    f32x4 wr = *(const f32x4*)(gw + (l * 8 + j) * 4);
    a0 += xf * wr[0];
    a1 += xf * wr[1];
    a2 += xf * wr[2];
    a3 += xf * wr[3];
  }
#pragma unroll
  for (int o = 32; o > 0; o >>= 1) {
    a0 += __shfl_xor(a0, o);
    a1 += __shfl_xor(a1, o);
    a2 += __shfl_xor(a2, o);
    a3 += __shfl_xor(a3, o);
  }
  a0 += gb[0];
  a1 += gb[1];
  a2 += gb[2];
  a3 += gb[3];
  float m = fmaxf(fmaxf(a0, a1), fmaxf(a2, a3));
  float e0 = expf(a0 - m), e1 = expf(a1 - m), e2 = expf(a2 - m), e3 = expf(a3 - m);
  float s = e0 + e1 + e2 + e3;
  if (l == 0) {
    float* gp = gates + (long)b * 4;
    gp[0] = e0 / s;
    gp[1] = e1 / s;
    gp[2] = e2 / s;
    gp[3] = e3 / s;
  }
}

__global__ __launch_bounds__(256) void bhist_k(const int* sid, int* bh) {
  int blk = blockIdx.x, t = threadIdx.x;
  __shared__ int h[cS];
  if (t < cS) h[t] = 0;
  __syncthreads();
  int s = sid[blk * 256 + t];
#pragma unroll
  for (int q = 0; q < cS; q++) {
    unsigned long long m = __ballot(s == q);
    if ((t & 63) == 0) atomicAdd(&h[q], __popcll(m));
  }
  __syncthreads();
  if (t < cS) bh[blk * cS + t] = h[t];
}

__global__ void bbase_k(const int* bh, int* base, int* cum) {
  __shared__ int tot[cS];
  int s = threadIdx.x;
  if (s < cS) {
    int run = 0;
    for (int b = 0; b < 64; b++) {
      base[b * cS + s] = run;
      run += bh[b * cS + s];
    }
    tot[s] = run;
  }
  __syncthreads();
  if (s == 0) {
    int run = 0;
    for (int q = 0; q < cS; q++) {
      cum[q] = run;
      run += tot[q];
    }
    cum[cS] = run;
  }
  __syncthreads();
  if (s < cS) {
    int c = cum[s];
    for (int b = 0; b < 64; b++) base[b * cS + s] += c;
  }
}

__global__ __launch_bounds__(256) void bscat_k(const int* sid, const int* base, int* perm) {
  int blk = blockIdx.x, t = threadIdx.x, w = t >> 6, l = t & 63;
  __shared__ int wc[4][cS];
  __shared__ int wb[4][cS];
  int s = sid[blk * 256 + t];
  int rank = 0;
#pragma unroll
  for (int q = 0; q < cS; q++) {
    unsigned long long m = __ballot(s == q);
    if (l == 0) wc[w][q] = __popcll(m);
    if (s == q) rank = __popcll(m & ((1ull << l) - 1ull));
  }
  __syncthreads();
  if (t < cS) {
    int run = 0;
#pragma unroll
    for (int ww = 0; ww < 4; ww++) {
      wb[ww][t] = run;
      run += wc[ww][t];
    }
  }
  __syncthreads();
  perm[base[blk * cS + s] + wb[w][s] + rank] = blk * 256 + t;
}

__global__ __launch_bounds__(256) void scenpart_k(const float* emb, const float* w1,
                                                  const float* b1, float* scp) {
  __shared__ float red[8][32];
  int s = blockIdx.x;
  int nl = threadIdx.x & 31;
  int n = blockIdx.y * 32 + nl;
  int dg = threadIdx.x >> 5;
  float a = 0.f;
#pragma unroll 4
  for (int d = dg * 64; d < dg * 64 + 64; d++) a += emb[s * cD + d] * w1[(long)(cD + d) * cDH + n];
  red[dg][nl] = a;
  __syncthreads();
  if (dg == 0) {
    float t = b1[n];
#pragma unroll
    for (int g = 0; g < 8; g++) t += red[g][nl];
    scp[s * cDH + n] = t;
  }
}

__global__ __launch_bounds__(256) void wsel_k(const float* sp, const float* scp, const float* w2,
                                              const int* sid, float* wsel) {
  int b = blockIdx.x * 4 + (threadIdx.x >> 6);
  int l = threadIdx.x & 63;
  float spv[4], w2v[4];
#pragma unroll
  for (int q = 0; q < 4; q++) {
    spv[q] = sp[(long)b * cDH + q * 64 + l];
    w2v[q] = w2[q * 64 + l];
  }
  float lg[8];
#pragma unroll
  for (int s = 0; s < 8; s++) {
    float acc = 0.f;
#pragma unroll
    for (int q = 0; q < 4; q++) {
      float v = spv[q] + scp[s * cDH + q * 64 + l];
      v = fmaxf(v, 0.f);
      acc += v * w2v[q];
    }
#pragma unroll
    for (int o = 32; o > 0; o >>= 1) acc += __shfl_xor(acc, o);
    lg[s] = acc;
  }
  float m = lg[0];
#pragma unroll
  for (int s = 1; s < 8; s++) m = fmaxf(m, lg[s]);
  float sum = 0.f;
#pragma unroll
  for (int s = 0; s < 8; s++) sum += expf(lg[s] - m);
  if (l == 0) {
    int s0 = sid[b];
    wsel[b] = expf(lg[s0] - m) / sum;
  }
}

__global__ __launch_bounds__(256) void cvt_shared_k(const float* sf, bf16* ss) {
  int i = blockIdx.x * 256 + threadIdx.x;
  int r = i >> 7, c = (i & 127) * 4;
  f32x4 v = *(const f32x4*)(sf + (long)r * cD + c);
  short4v o;
#pragma unroll
  for (int j = 0; j < 4; j++) o[j] = __builtin_bit_cast(short, tob(v[j]));
  *(short4v*)(ss + (long)r * 1024 + c) = o;
}

// =====================  launcher  =====================
extern "C" void kernel_launch(void* const* d_in, const int* in_sizes, int n_in, void* d_out,
                              int out_size, void* d_ws, size_t ws_size, hipStream_t stream) {
  const void* x = d_in[0];
  const int* sid = (const int*)d_in[1];

  char* ws = (char*)d_ws;
  size_t off = 0;
  auto alloc = [&](size_t bytes) -> void* {
    void* p = ws + off;
    off += (bytes + 255) & ~(size_t)255;
    return p;
  };
  int* g_flag = (int*)alloc(64);
  float* g_gates = (float*)alloc((size_t)cB * 4 * 4);
  float* g_wsel = (float*)alloc((size_t)cB * 4);
  int* g_perm = (int*)alloc((size_t)cB * 4);
  int* g_bh = (int*)alloc(64 * cS * 4);
  int* g_base = (int*)alloc(64 * cS * 4);
  int* g_cum = (int*)alloc(64);
  float* g_scp = (float*)alloc((size_t)cS * cDH * 4);
  float* g_small = (float*)alloc((size_t)300000 * 4);
  bf16* g_xb = (bf16*)alloc((size_t)cB * cD * 2);
  bf16* w1t = (bf16*)alloc((size_t)cE * cH * cD * 2);
  bf16* w2cat = (bf16*)alloc((size_t)cD * 4096 * 2);
  bf16* s1t = (bf16*)alloc((size_t)cS * cH * cD * 2);
  bf16* s2t = (bf16*)alloc((size_t)cS * cD * cH * 2);
  bf16* a1t = (bf16*)alloc((size_t)cDH * cD * 2);
  bf16* owpair = (bf16*)alloc((size_t)1024 * 1024 * 2);
  bf16* g_ss = (bf16*)alloc((size_t)cB * 1024 * 2);
  size_t fixed_end = off;
  const size_t MB = 1024ull * 1024ull;
  const bool BIG = (ws_size == 0) || (fixed_end + 135 * MB <= ws_size);
  char* g_big = (char*)alloc(BIG ? 135 * MB : 68 * MB);
  (void)in_sizes;
  (void)n_in;
  (void)out_size;

  dim3 blk(256);
  probe_k<<<1, blk, 0, stream>>>(x, g_flag);
  cvtx_k<<<cB * cD / 8 / 256, blk, 0, stream>>>(x, g_xb, g_flag);

  const int O_GW = 0, O_GB = 2048, O_SB1 = 2052, O_SB2 = 6148, O_PB1 = 8196, O_PB2 = 16388,
            O_EMB = 20484, O_AW1 = 24580, O_AB1 = 286724, O_AW2 = 286980, O_OB = 287236,
            O_END = 287748;
  {
    CvtDesc d;
    const void* srcs[11] = {d_in[2],  d_in[3],  d_in[5],  d_in[7],  d_in[9], d_in[11],
                            d_in[12], d_in[13], d_in[14], d_in[15], d_in[18]};
    int offs[12] = {O_GW, O_GB, O_SB1, O_SB2, O_PB1, O_PB2, O_EMB, O_AW1, O_AB1, O_AW2, O_OB,
                    O_END};
    for (int i = 0; i < 11; i++) d.src[i] = srcs[i];
    for (int i = 0; i < 12; i++) d.off[i] = offs[i];
    cvt_smalls_k<<<(O_END + 255) / 256, blk, 0, stream>>>(d, g_flag, g_small);
  }

  transpose_k<<<dim3(cH / 32, cD / 32, cE), blk, 0, stream>>>(d_in[4], w1t, cH, cD, 0,
                                                              (long)cD * cH, (long)cH * cD, g_flag);
  transpose_k<<<dim3(cD / 32, cH / 32, cE), blk, 0, stream>>>(d_in[6], w2cat, cD, 4096, 0,
                                                              (long)cH * cD, 1024, g_flag);
  transpose_k<<<dim3(cH / 32, cD / 32, cS), blk, 0, stream>>>(d_in[8], s1t, cH, cD, 0,
                                                              (long)cD * cH, (long)cH * cD, g_flag);
  transpose_k<<<dim3(cD / 32, cH / 32, cS), blk, 0, stream>>>(d_in[10], s2t, cD, cH, 0,
                                                              (long)cH * cD, (long)cD * cH, g_flag);
  transpose_k<<<dim3(cDH / 32, cD / 32, 1), blk, 0, stream>>>(d_in[13], a1t, cDH, cD, 0, 0, 0,
                                                              g_flag);
  owt_k<<<dim3(cD / 32, cD / 32, 4), blk, 0, stream>>>(d_in[17], owpair, g_flag);

  gates_k<<<cB / 4, blk, 0, stream>>>(g_xb, g_small + O_GW, g_small + O_GB, g_gates);
  bhist_k<<<cB / 256, blk, 0, stream>>>(sid, g_bh);
  bbase_k<<<1, 64, 0, stream>>>(g_bh, g_base, g_cum);
  bscat_k<<<cB / 256, blk, 0, stream>>>(sid, g_base, g_perm);

  if (BIG) {
    bf16* h4 = (bf16*)g_big;     // [16384,4096]
    float* sp = (float*)g_big;   // [16384,256] (after h4 dead)
    bf16* hspec = (bf16*)g_big;  // [16384,1024] (after sp dead)
    {
      GArgs a{};
      a.A = g_xb; a.lda = cD; a.Bt = w1t; a.ldb = cD;
      a.C = h4; a.ldc = 4096; a.M = cB; a.N = 4096; a.K = cD;
      a.bias = g_small + O_SB1; a.gates = g_gates;
      gemm_k<6, false, false, false><<<dim3(32, cB / 128), blk, 0, stream>>>(a);
    }
    {
      GArgs a{};
      a.A = h4; a.lda = 4096; a.Bt = w2cat; a.ldb = 4096;
      a.C = g_ss; a.ldc = 1024; a.M = cB; a.N = cD; a.K = 4096;
      a.bias = g_small + O_SB2; a.gates = g_gates;
      gemm_k<7, false, false, false><<<dim3(cD / 128, cB / 128), blk, 0, stream>>>(a);
    }
    {
      GArgs a{};
      a.A = g_ss; a.lda = 1024; a.Bt = a1t; a.ldb = cD;
      a.C = sp; a.ldc = cDH; a.M = cB; a.N = cDH; a.K = cD;
      gemm_k<3, false, false, false><<<dim3(cDH / 128, cB / 128), blk, 0, stream>>>(a);
    }
    scenpart_k<<<dim3(cS, 8), blk, 0, stream>>>(g_small + O_EMB, g_small + O_AW1, g_small + O_AB1,
                                                g_scp);
    wsel_k<<<cB / 4, blk, 0, stream>>>(sp, g_scp, g_small + O_AW2, sid, g_wsel);
    {
      GArgs a{};
      a.A = g_xb; a.lda = cD; a.Bt = s1t; a.ldb = cD; a.bt_stride = (long)cH * cD;
      a.C = hspec; a.ldc = cH; a.M = cB; a.N = cH; a.K = cD;
      a.bias = g_small + O_PB1; a.bias_stride = cH;
      a.perm = g_perm; a.cum = g_cum;
      gemm_k<1, true, true, false><<<dim3(cH / 128, cB / 128, cS), blk, 0, stream>>>(a);
    }
    {
      GArgs a{};
      a.A = hspec; a.lda = cH; a.Bt = s2t; a.ldb = cH; a.bt_stride = (long)cD * cH;
      a.C = g_ss + 512; a.ldc = 1024; a.M = cB; a.N = cD; a.K = cH;
      a.bias = g_small + O_PB2; a.bias_stride = cD;
      a.perm = g_perm; a.cum = g_cum;
      gemm_k<4, true, false, true><<<dim3(cD / 128, cB / 128, cS), blk, 0, stream>>>(a);
    }
    {
      // merged P1+out: B = owpair [1024 rows][K=1024]
      GArgs a{};
      a.A = g_ss; a.lda = 1024; a.Bt = owpair; a.ldb = 1024;
      a.C = d_out; a.ldc = cD; a.M = cB; a.N = 1024; a.K = 1024;
      a.bias = g_small + O_OB; a.wsel = g_wsel; a.dflag = g_flag;
      gemm_k<9, false, false, false><<<dim3(8, cB / 128), blk, 0, stream>>>(a);
    }
  } else {
    // fallback: sequential-expert structure inside 68MB scratch
    float* f32a = (float*)g_big;            // [16384,512] f32
    bf16* hbuf = (bf16*)(g_big + 34 * MB);  // [16384,1024] bf16
    for (int e = 0; e < cE; e++) {
      GArgs a1{};
      a1.A = g_xb; a1.lda = cD; a1.Bt = w1t + (size_t)e * cH * cD; a1.ldb = cD;
      a1.C = hbuf; a1.ldc = cH; a1.M = cB; a1.N = cH; a1.K = cD;
      a1.bias = g_small + O_SB1 + e * cH;
      gemm_k<1, false, false, false><<<dim3(cH / 128, cB / 128), blk, 0, stream>>>(a1);
      GArgs a2{};
      a2.A = hbuf; a2.lda = cH; a2.Bt = w2cat + (size_t)e * 1024; a2.ldb = 4096;
      a2.C = f32a; a2.ldc = cD; a2.M = cB; a2.N = cD; a2.K = cH;
      a2.bias = g_small + O_SB2 + e * cD; a2.gates = g_gates; a2.eidx = e;
      gemm_k<2, false, false, false><<<dim3(cD / 128, cB / 128), blk, 0, stream>>>(a2);
    }
    cvt_shared_k<<<cB * 128 / 256, blk, 0, stream>>>(f32a, g_ss);
    {
      GArgs a{};
      a.A = g_xb; a.lda = cD; a.Bt = s1t; a.ldb = cD; a.bt_stride = (long)cH * cD;
      a.C = hbuf; a.ldc = cH; a.M = cB; a.N = cH; a.K = cD;
      a.bias = g_small + O_PB1; a.bias_stride = cH;
      a.perm = g_perm; a.cum = g_cum;
      gemm_k<1, true, true, false><<<dim3(cH / 128, cB / 128, cS), blk, 0, stream>>>(a);
    }
    {
      GArgs a{};
      a.A = hbuf; a.lda = cH; a.Bt = s2t; a.ldb = cH; a.bt_stride = (long)cD * cH;
      a.C = g_ss + 512; a.ldc = 1024; a.M = cB; a.N = cD; a.K = cH;
      a.bias = g_small + O_PB2; a.bias_stride = cD;
      a.perm = g_perm; a.cum = g_cum;
      gemm_k<4, true, false, true><<<dim3(cD / 128, cB / 128, cS), blk, 0, stream>>>(a);
    }
    {
      GArgs a{};
      a.A = g_ss; a.lda = 1024; a.Bt = a1t; a.ldb = cD;
      a.C = f32a; a.ldc = cDH; a.M = cB; a.N = cDH; a.K = cD;
      gemm_k<3, false, false, false><<<dim3(cDH / 128, cB / 128), blk, 0, stream>>>(a);
    }
    scenpart_k<<<dim3(cS, 8), blk, 0, stream>>>(g_small + O_EMB, g_small + O_AW1, g_small + O_AB1,
                                                g_scp);
    wsel_k<<<cB / 4, blk, 0, stream>>>(f32a, g_scp, g_small + O_AW2, sid, g_wsel);
    {
      GArgs a{};
      a.A = g_ss; a.lda = 1024; a.Bt = owpair; a.ldb = 1024;
      a.C = d_out; a.ldc = cD; a.M = cB; a.N = 1024; a.K = 1024;
      a.bias = g_small + O_OB; a.wsel = g_wsel; a.dflag = g_flag;
      gemm_k<9, false, false, false><<<dim3(8, cB / 128), blk, 0, stream>>>(a);
    }
  }
}